// Round 14
// baseline (261.354 us; speedup 1.0000x reference)
//
#include <hip/hip_runtime.h>
#include <hip/hip_bf16.h>

typedef __bf16 bf16;
typedef __attribute__((ext_vector_type(8))) __bf16 b16x8;
typedef __attribute__((ext_vector_type(4))) float f32x4;
typedef __attribute__((ext_vector_type(4))) int i32x4;

#define MFMA16(a, b, c) __builtin_amdgcn_mfma_f32_16x16x32_bf16((a), (b), (c), 0, 0, 0)

// q pre-scale: 1/sqrt(32) * log2(e)  (scores then feed exp2 directly)
#define QSCALE 0.25501568077324936f
#define MCONST -1442.6950408889634f

// ====== launch 1: proj GEMM (fp32->bf16 staging) || v-trans || Wfc conv || maskf ====
__global__ void __launch_bounds__(256) k_prep(const float* __restrict__ q,
                                              const float* __restrict__ kk,
                                              const float* __restrict__ Wqk,
                                              const float* __restrict__ v,
                                              const float* __restrict__ Wfc,
                                              const int* __restrict__ svalid,
                                              bf16* __restrict__ ph,
                                              bf16* __restrict__ vT,
                                              bf16* __restrict__ Wfcb,
                                              float* __restrict__ maskf) {
    __shared__ __align__(16) char smem[10240];
    int tid = threadIdx.x;
    int idx = blockIdx.x;
    if (idx < 1024) {
        // ---- proj: ph[m][256] = [q;k][m][:] @ Wqk^T  (q rows pre-scaled by QSCALE) ----
        bf16(*sA)[40] = (bf16(*)[40])smem;
        bf16(*sB)[40] = (bf16(*)[40])(smem + 5120);
        int w = tid >> 6, l = tid & 63, lg = l >> 4, ll = l & 15;
        int wm = w >> 1, wn = w & 1;
        int m0 = (idx & 255) * 64, n0 = (idx >> 8) * 64;
        const float* A = (m0 < 8192) ? q + (size_t)m0 * 256 : kk + (size_t)(m0 - 8192) * 256;
        float osc = (m0 < 8192) ? QSCALE : 1.0f;
        f32x4 acc[2][2] = {};
        int ar = tid >> 2, ac = (tid & 3) * 8;
#pragma unroll
        for (int k0 = 0; k0 < 256; k0 += 32) {
            __syncthreads();
            f32x4 a0 = *(const f32x4*)(A + (size_t)ar * 256 + k0 + ac);
            f32x4 a1 = *(const f32x4*)(A + (size_t)ar * 256 + k0 + ac + 4);
            f32x4 b0 = *(const f32x4*)(Wqk + (size_t)(n0 + ar) * 256 + k0 + ac);
            f32x4 b1 = *(const f32x4*)(Wqk + (size_t)(n0 + ar) * 256 + k0 + ac + 4);
            b16x8 av, bv;
#pragma unroll
            for (int i = 0; i < 4; i++) {
                av[i] = (bf16)a0[i]; av[4 + i] = (bf16)a1[i];
                bv[i] = (bf16)b0[i]; bv[4 + i] = (bf16)b1[i];
            }
            *(b16x8*)&sA[ar][ac] = av;
            *(b16x8*)&sB[ar][ac] = bv;
            __syncthreads();
            b16x8 af[2], bfr[2];
#pragma unroll
            for (int f = 0; f < 2; f++) {
                af[f] = *(b16x8*)&sA[wm * 32 + f * 16 + ll][8 * lg];
                bfr[f] = *(b16x8*)&sB[wn * 32 + f * 16 + ll][8 * lg];
            }
#pragma unroll
            for (int i = 0; i < 2; i++)
#pragma unroll
                for (int j = 0; j < 2; j++) acc[i][j] = MFMA16(af[i], bfr[j], acc[i][j]);
        }
#pragma unroll
        for (int i = 0; i < 2; i++)
#pragma unroll
            for (int j = 0; j < 2; j++) {
                int row = m0 + wm * 32 + i * 16 + lg * 4;
                int col = n0 + wn * 32 + j * 16 + ll;
#pragma unroll
                for (int r = 0; r < 4; r++)
                    ph[(size_t)(row + r) * 256 + col] = (bf16)(acc[i][j][r] * osc);
            }
    } else if (idx < 2048) {
        // ---- v (B,Ns,256) fp32 -> vT[(b*8+h)*32+d][k] bf16 ----
        bf16(*sT)[72] = (bf16(*)[72])smem;
        int i2 = idx - 1024;
        int bh = i2 >> 5, b = bh >> 3, h = bh & 7;
        int ns0 = (i2 & 31) * 64;
        int ns = tid >> 2;
        int dp = (tid & 3) * 8;
        const float* sp = v + ((size_t)(b * 2048 + ns0 + ns)) * 256 + h * 32 + dp;
        f32x4 a = *(const f32x4*)sp;
        f32x4 c = *(const f32x4*)(sp + 4);
#pragma unroll
        for (int i = 0; i < 4; i++) sT[dp + i][ns] = (bf16)a[i];
#pragma unroll
        for (int i = 0; i < 4; i++) sT[dp + 4 + i][ns] = (bf16)c[i];
        __syncthreads();
        int d = tid >> 3;
        int nc = (tid & 7) * 8;
        b16x8 o = *(b16x8*)&sT[d][nc];
        *(b16x8*)(vT + ((size_t)bh * 32 + d) * 2048 + ns0 + nc) = o;
    } else if (idx < 2080) {
        // ---- Wfc fp32 -> bf16 ----
        int i = (idx - 2048) * 2048 + tid * 8;
        f32x4 a = *(const f32x4*)(Wfc + i);
        f32x4 b = *(const f32x4*)(Wfc + i + 4);
        b16x8 o;
        o[0] = (bf16)a[0]; o[1] = (bf16)a[1]; o[2] = (bf16)a[2]; o[3] = (bf16)a[3];
        o[4] = (bf16)b[0]; o[5] = (bf16)b[1]; o[6] = (bf16)b[2]; o[7] = (bf16)b[3];
        *(b16x8*)(Wfcb + i) = o;
    } else {
        // ---- mask int -> float*MCONST (8192 values) ----
#pragma unroll
        for (int c = 0; c < 32; c++) {
            int i = c * 256 + tid;
            maskf[i] = MCONST * (float)svalid[i];
        }
    }
}

// ====== launch 2: fused attn — barrier-free, direct K/V fragment loads, NT stores ====
// K/V fragments are warp-uniform (L1-broadcast across the 4 warps) and shared by the
// 32 qt-blocks of each (b,h) (L2-hit; L2 stays clean thanks to NT attn stores).
// Only LDS use: wave-local sPf for the P transpose (256B-contiguous stores) + PV frags.
__global__ void __launch_bounds__(256) k_attn(const bf16* __restrict__ ph,
                                              const bf16* __restrict__ vT,
                                              const float* __restrict__ maskf,
                                              bf16* __restrict__ xO,
                                              float* __restrict__ attn) {
    __shared__ __align__(16) float sPf[4][16][68];  // 17408 B total
    int tid = threadIdx.x;
    int w = tid >> 6, l = tid & 63, lg = l >> 4, ll = l & 15;
    int bh = blockIdx.x >> 5, qt = blockIdx.x & 31;
    int b = bh >> 3, h = bh & 7;
    int qrow0 = qt * 64 + w * 16;
    b16x8 qf = *(const b16x8*)(ph + (size_t)(b * 2048 + qrow0 + ll) * 256 + h * 32 + 8 * lg);
    const float* mrow = maskf + b * 2048;
    // per-lane fragment bases
    const bf16* kfb = ph + (size_t)(8192 + b * 2048) * 256 + h * 32 + 8 * lg;  // + (kt+n*16+ll)*256
    const bf16* vfb = vT + (size_t)(bh * 32) * 2048 + 8 * lg;                  // + (j*16+ll)*2048 + kt + ks*32
    float lsum = 0.f;
    // ---- pass A: row sums (direct kf loads, prefetched one tile ahead) ----
    {
        b16x8 kf[4], kn[4];
#pragma unroll
        for (int n = 0; n < 4; n++)
            kf[n] = *(const b16x8*)(kfb + (size_t)(n * 16 + ll) * 256);
        for (int kt = 0; kt < 2048; kt += 64) {
            bool more = (kt + 64) < 2048;
            if (more) {
#pragma unroll
                for (int n = 0; n < 4; n++)
                    kn[n] = *(const b16x8*)(kfb + (size_t)(kt + 64 + n * 16 + ll) * 256);
            }
            f32x4 s[4];
#pragma unroll
            for (int n = 0; n < 4; n++) {
                f32x4 z = {};
                s[n] = MFMA16(kf[n], qf, z);
            }
#pragma unroll
            for (int n = 0; n < 4; n++) {
                f32x4 mk = *(const f32x4*)&mrow[kt + n * 16 + lg * 4];
#pragma unroll
                for (int r = 0; r < 4; r++) lsum += exp2f(s[n][r] + mk[r]);
            }
#pragma unroll
            for (int n = 0; n < 4; n++) kf[n] = kn[n];
        }
    }
    lsum += __shfl_xor(lsum, 16, 64);
    lsum += __shfl_xor(lsum, 32, 64);
    float linv = 1.f / lsum;
    // ---- pass B: recompute, NT-write normalized attn, accumulate O = P@V ----
    f32x4 o[2] = {};
    float* outb = attn + (size_t)(bh * 2048 + qrow0) * 2048;
    b16x8 kf[4], kn[4], vf[2][2], vn[2][2];
#pragma unroll
    for (int n = 0; n < 4; n++)
        kf[n] = *(const b16x8*)(kfb + (size_t)(n * 16 + ll) * 256);
#pragma unroll
    for (int ks = 0; ks < 2; ks++)
#pragma unroll
        for (int j = 0; j < 2; j++)
            vf[ks][j] = *(const b16x8*)(vfb + (size_t)(j * 16 + ll) * 2048 + ks * 32);
    for (int kt = 0; kt < 2048; kt += 64) {
        bool more = (kt + 64) < 2048;
        if (more) {
#pragma unroll
            for (int n = 0; n < 4; n++)
                kn[n] = *(const b16x8*)(kfb + (size_t)(kt + 64 + n * 16 + ll) * 256);
#pragma unroll
            for (int ks = 0; ks < 2; ks++)
#pragma unroll
                for (int j = 0; j < 2; j++)
                    vn[ks][j] = *(const b16x8*)(vfb + (size_t)(j * 16 + ll) * 2048 + kt + 64 + ks * 32);
        }
        f32x4 s[4];
#pragma unroll
        for (int n = 0; n < 4; n++) {
            f32x4 z = {};
            s[n] = MFMA16(kf[n], qf, z);
        }
#pragma unroll
        for (int n = 0; n < 4; n++) {
            f32x4 mk = *(const f32x4*)&mrow[kt + n * 16 + lg * 4];
            f32x4 ov;
#pragma unroll
            for (int r = 0; r < 4; r++) ov[r] = exp2f(s[n][r] + mk[r]) * linv;
            *(f32x4*)&sPf[w][ll][n * 16 + lg * 4] = ov;  // ds_write_b128 (wave-local)
        }
        // contiguous 256B f32x4 NON-TEMPORAL stores (bypass L2 allocate)
#pragma unroll
        for (int j = 0; j < 4; j++) {
            int row16 = lg + 4 * j;
            f32x4 v = *(f32x4*)&sPf[w][row16][ll * 4];
            __builtin_nontemporal_store(v, (f32x4*)(outb + (size_t)row16 * 2048 + kt + ll * 4));
        }
        // PV accumulate: fragment from f32 sPf, cvt to bf16 in-register
#pragma unroll
        for (int ks = 0; ks < 2; ks++) {
            f32x4 p0 = *(f32x4*)&sPf[w][ll][ks * 32 + 8 * lg];
            f32x4 p1 = *(f32x4*)&sPf[w][ll][ks * 32 + 8 * lg + 4];
            b16x8 pf;
#pragma unroll
            for (int i = 0; i < 4; i++) {
                pf[i] = (bf16)p0[i];
                pf[4 + i] = (bf16)p1[i];
            }
#pragma unroll
            for (int j = 0; j < 2; j++) o[j] = MFMA16(pf, vf[ks][j], o[j]);
        }
        if (more) {
#pragma unroll
            for (int n = 0; n < 4; n++) kf[n] = kn[n];
#pragma unroll
            for (int ks = 0; ks < 2; ks++)
#pragma unroll
                for (int j = 0; j < 2; j++) vf[ks][j] = vn[ks][j];
        }
    }
#pragma unroll
    for (int r = 0; r < 4; r++) {
        int row = b * 2048 + qrow0 + lg * 4 + r;
#pragma unroll
        for (int j = 0; j < 2; j++) {
            int col = h * 32 + j * 16 + ll;
            xO[(size_t)(row >> 5) * 16384 + (row & 31) * 256 + col] = (bf16)o[j][r];
        }
    }
}

// ====== launch 3: FC full-row + bias + idt + LayerNorm (xO hole-layout) =============
__global__ void __launch_bounds__(256) k_fcln(const bf16* __restrict__ xO,
                                              const bf16* __restrict__ Wfcb,
                                              const float* __restrict__ bias,
                                              const float* __restrict__ idt,
                                              const float* __restrict__ lnw,
                                              const float* __restrict__ lnb,
                                              float* __restrict__ out) {
    __shared__ __align__(16) bf16 sA[32][264];
    __shared__ __align__(16) bf16 sB[256][40];
    __shared__ float sRed[4][32][2];
    int tid = threadIdx.x;
    int w = tid >> 6, l = tid & 63, lg = l >> 4, ll = l & 15;
    int t = blockIdx.x;  // rows 32t..32t+31
#pragma unroll
    for (int c = 0; c < 4; c++) {
        int col = (tid & 7) * 8 + c * 64;
        *(b16x8*)&sA[tid >> 3][col] =
            *(const b16x8*)(xO + (size_t)t * 16384 + (tid >> 3) * 256 + col);
    }
    __syncthreads();
    f32x4 acc[2][4] = {};
#pragma unroll
    for (int k0 = 0; k0 < 256; k0 += 32) {
        if (k0) __syncthreads();
#pragma unroll
        for (int c = 0; c < 4; c++)
            *(b16x8*)&sB[tid][c * 8] = *(const b16x8*)(Wfcb + (size_t)tid * 256 + k0 + c * 8);
        __syncthreads();
        b16x8 af[2];
#pragma unroll
        for (int i = 0; i < 2; i++) af[i] = *(b16x8*)&sA[i * 16 + ll][k0 + 8 * lg];
#pragma unroll
        for (int j = 0; j < 4; j++) {
            b16x8 bfr = *(b16x8*)&sB[w * 64 + j * 16 + ll][8 * lg];
#pragma unroll
            for (int i = 0; i < 2; i++) acc[i][j] = MFMA16(af[i], bfr, acc[i][j]);
        }
    }
    float bcol[4], wcol[4], bbl[4];
#pragma unroll
    for (int j = 0; j < 4; j++) {
        int col = w * 64 + j * 16 + ll;
        bcol[j] = bias[col];
        wcol[j] = lnw[col];
        bbl[j] = lnb[col];
    }
#pragma unroll
    for (int i = 0; i < 2; i++)
#pragma unroll
        for (int r = 0; r < 4; r++) {
            int row32 = i * 16 + lg * 4 + r;
            int grow = t * 32 + row32;
            float a = 0.f, b2 = 0.f;
#pragma unroll
            for (int j = 0; j < 4; j++) {
                float xv = acc[i][j][r] + bcol[j] + idt[(size_t)grow * 256 + w * 64 + j * 16 + ll];
                acc[i][j][r] = xv;
                a += xv;
                b2 += xv * xv;
            }
#pragma unroll
            for (int off = 1; off < 16; off <<= 1) {
                a += __shfl_xor(a, off, 64);
                b2 += __shfl_xor(b2, off, 64);
            }
            if (ll == 0) {
                sRed[w][row32][0] = a;
                sRed[w][row32][1] = b2;
            }
        }
    __syncthreads();
#pragma unroll
    for (int i = 0; i < 2; i++)
#pragma unroll
        for (int r = 0; r < 4; r++) {
            int row32 = i * 16 + lg * 4 + r;
            int grow = t * 32 + row32;
            float st = sRed[0][row32][0] + sRed[1][row32][0] + sRed[2][row32][0] + sRed[3][row32][0];
            float st2 = sRed[0][row32][1] + sRed[1][row32][1] + sRed[2][row32][1] + sRed[3][row32][1];
            float mu = st * (1.f / 256.f);
            float var = st2 * (1.f / 256.f) - mu * mu;
            float rstd = rsqrtf(var + 1e-5f);
#pragma unroll
            for (int j = 0; j < 4; j++)
                out[(size_t)grow * 256 + w * 64 + j * 16 + ll] =
                    (acc[i][j][r] - mu) * rstd * wcol[j] + bbl[j];
        }
}

extern "C" void kernel_launch(void* const* d_in, const int* in_sizes, int n_in,
                              void* d_out, int out_size, void* d_ws, size_t ws_size,
                              hipStream_t stream) {
    const float* k_in = (const float*)d_in[0];
    const float* v_in = (const float*)d_in[1];
    const float* q_in = (const float*)d_in[2];
    const float* idt  = (const float*)d_in[3];
    const int* svalid = (const int*)d_in[4];
    const float* Wqk  = (const float*)d_in[5];
    const float* Wfc  = (const float*)d_in[6];
    const float* bfc  = (const float*)d_in[7];
    const float* lnw  = (const float*)d_in[8];
    const float* lnb  = (const float*)d_in[9];

    float* out_ln = (float*)d_out;               // 8192*256 f32
    float* attn = out_ln + 2097152;              // (B*H, Nq, Ns) f32

    // workspace layout (~12.2 MB)
    char* ws = (char*)d_ws;
    bf16* ph     = (bf16*)ws;                    // 16384*256 bf16 (q rows pre-scaled)
    bf16* vT     = (bf16*)(ws + 8388608);        // 32*32*2048 bf16 = 4 MB
    bf16* Wfcb   = (bf16*)(ws + 12582912);       // 65536 bf16
    float* maskf = (float*)(ws + 12713984);      // 8192 f32

    // xO parks in out_ln region, tile t at byte 32768*t (fcln block t is sole reader
    // and sole overwriter after LDS staging) -> race-free.
    bf16* xO = (bf16*)out_ln;

    k_prep<<<2081, 256, 0, stream>>>(q_in, k_in, Wqk, v_in, Wfc, svalid, ph, vT, Wfcb, maskf);
    k_attn<<<1024, 256, 0, stream>>>(ph, vT, maskf, xO, attn);
    k_fcln<<<256, 256, 0, stream>>>(xO, Wfcb, bfc, idt, lnw, lnb, out_ln);
}

// Round 15
// 171.811 us; speedup vs baseline: 1.5212x; 1.5212x over previous
//
#include <hip/hip_runtime.h>
#include <hip/hip_bf16.h>

typedef __bf16 bf16;
typedef __attribute__((ext_vector_type(8))) __bf16 b16x8;
typedef __attribute__((ext_vector_type(4))) float f32x4;
typedef __attribute__((ext_vector_type(4))) int i32x4;

#define MFMA16(a, b, c) __builtin_amdgcn_mfma_f32_16x16x32_bf16((a), (b), (c), 0, 0, 0)

// q pre-scale: 1/sqrt(32) * log2(e)  (scores then feed exp2 directly)
#define QSCALE 0.25501568077324936f
#define MCONST -1442.6950408889634f

// ====== launch 1: proj GEMM (fp32->bf16 staging) || v-trans || Wfc conv || maskf ====
__global__ void __launch_bounds__(256) k_prep(const float* __restrict__ q,
                                              const float* __restrict__ kk,
                                              const float* __restrict__ Wqk,
                                              const float* __restrict__ v,
                                              const float* __restrict__ Wfc,
                                              const int* __restrict__ svalid,
                                              bf16* __restrict__ ph,
                                              bf16* __restrict__ vT,
                                              bf16* __restrict__ Wfcb,
                                              float* __restrict__ maskf) {
    __shared__ __align__(16) char smem[10240];
    int tid = threadIdx.x;
    int idx = blockIdx.x;
    if (idx < 1024) {
        // ---- proj: ph[m][256] = [q;k][m][:] @ Wqk^T  (q rows pre-scaled by QSCALE) ----
        bf16(*sA)[40] = (bf16(*)[40])smem;
        bf16(*sB)[40] = (bf16(*)[40])(smem + 5120);
        int w = tid >> 6, l = tid & 63, lg = l >> 4, ll = l & 15;
        int wm = w >> 1, wn = w & 1;
        int m0 = (idx & 255) * 64, n0 = (idx >> 8) * 64;
        const float* A = (m0 < 8192) ? q + (size_t)m0 * 256 : kk + (size_t)(m0 - 8192) * 256;
        float osc = (m0 < 8192) ? QSCALE : 1.0f;
        f32x4 acc[2][2] = {};
        int ar = tid >> 2, ac = (tid & 3) * 8;
#pragma unroll
        for (int k0 = 0; k0 < 256; k0 += 32) {
            __syncthreads();
            f32x4 a0 = *(const f32x4*)(A + (size_t)ar * 256 + k0 + ac);
            f32x4 a1 = *(const f32x4*)(A + (size_t)ar * 256 + k0 + ac + 4);
            f32x4 b0 = *(const f32x4*)(Wqk + (size_t)(n0 + ar) * 256 + k0 + ac);
            f32x4 b1 = *(const f32x4*)(Wqk + (size_t)(n0 + ar) * 256 + k0 + ac + 4);
            b16x8 av, bv;
#pragma unroll
            for (int i = 0; i < 4; i++) {
                av[i] = (bf16)a0[i]; av[4 + i] = (bf16)a1[i];
                bv[i] = (bf16)b0[i]; bv[4 + i] = (bf16)b1[i];
            }
            *(b16x8*)&sA[ar][ac] = av;
            *(b16x8*)&sB[ar][ac] = bv;
            __syncthreads();
            b16x8 af[2], bfr[2];
#pragma unroll
            for (int f = 0; f < 2; f++) {
                af[f] = *(b16x8*)&sA[wm * 32 + f * 16 + ll][8 * lg];
                bfr[f] = *(b16x8*)&sB[wn * 32 + f * 16 + ll][8 * lg];
            }
#pragma unroll
            for (int i = 0; i < 2; i++)
#pragma unroll
                for (int j = 0; j < 2; j++) acc[i][j] = MFMA16(af[i], bfr[j], acc[i][j]);
        }
#pragma unroll
        for (int i = 0; i < 2; i++)
#pragma unroll
            for (int j = 0; j < 2; j++) {
                int row = m0 + wm * 32 + i * 16 + lg * 4;
                int col = n0 + wn * 32 + j * 16 + ll;
#pragma unroll
                for (int r = 0; r < 4; r++)
                    ph[(size_t)(row + r) * 256 + col] = (bf16)(acc[i][j][r] * osc);
            }
    } else if (idx < 2048) {
        // ---- v (B,Ns,256) fp32 -> vT[(b*8+h)*32+d][k] bf16 ----
        bf16(*sT)[72] = (bf16(*)[72])smem;
        int i2 = idx - 1024;
        int bh = i2 >> 5, b = bh >> 3, h = bh & 7;
        int ns0 = (i2 & 31) * 64;
        int ns = tid >> 2;
        int dp = (tid & 3) * 8;
        const float* sp = v + ((size_t)(b * 2048 + ns0 + ns)) * 256 + h * 32 + dp;
        f32x4 a = *(const f32x4*)sp;
        f32x4 c = *(const f32x4*)(sp + 4);
#pragma unroll
        for (int i = 0; i < 4; i++) sT[dp + i][ns] = (bf16)a[i];
#pragma unroll
        for (int i = 0; i < 4; i++) sT[dp + 4 + i][ns] = (bf16)c[i];
        __syncthreads();
        int d = tid >> 3;
        int nc = (tid & 7) * 8;
        b16x8 o = *(b16x8*)&sT[d][nc];
        *(b16x8*)(vT + ((size_t)bh * 32 + d) * 2048 + ns0 + nc) = o;
    } else if (idx < 2080) {
        // ---- Wfc fp32 -> bf16 ----
        int i = (idx - 2048) * 2048 + tid * 8;
        f32x4 a = *(const f32x4*)(Wfc + i);
        f32x4 b = *(const f32x4*)(Wfc + i + 4);
        b16x8 o;
        o[0] = (bf16)a[0]; o[1] = (bf16)a[1]; o[2] = (bf16)a[2]; o[3] = (bf16)a[3];
        o[4] = (bf16)b[0]; o[5] = (bf16)b[1]; o[6] = (bf16)b[2]; o[7] = (bf16)b[3];
        *(b16x8*)(Wfcb + i) = o;
    } else {
        // ---- mask int -> float*MCONST (8192 values) ----
#pragma unroll
        for (int c = 0; c < 32; c++) {
            int i = c * 256 + tid;
            maskf[i] = MCONST * (float)svalid[i];
        }
    }
}

// ====== launch 2: fused attn, async-stage + NT stores + XCD-aware block swizzle =====
// Swizzle: xcd = bid&7 serves bh in [xcd*4, xcd*4+4) -> K/V panels (~1MB) fit that
// XCD's 4MB L2 and stay resident across all 32 qt-blocks and both passes.
__global__ void __launch_bounds__(256) k_attn(const bf16* __restrict__ ph,
                                              const bf16* __restrict__ vT,
                                              const float* __restrict__ maskf,
                                              bf16* __restrict__ xO,
                                              float* __restrict__ attn) {
    __shared__ __align__(16) bf16 sK[64][40];       // 5120
    __shared__ __align__(16) bf16 sV[32][72];       // 4608
    __shared__ __align__(16) float sPf[4][16][68];  // 17408  (total 26.5 KB)
    int tid = threadIdx.x;
    int w = tid >> 6, l = tid & 63, lg = l >> 4, ll = l & 15;
    int swz = (blockIdx.x & 7) * 128 + (blockIdx.x >> 3);  // bijective (1024 % 8 == 0)
    int bh = swz >> 5, qt = swz & 31;
    int b = bh >> 3, h = bh & 7;
    int qrow0 = qt * 64 + w * 16;
    b16x8 qf = *(const b16x8*)(ph + (size_t)(b * 2048 + qrow0 + ll) * 256 + h * 32 + 8 * lg);
    const float* mrow = maskf + b * 2048;
    const bf16* kbase = ph + (size_t)(8192 + b * 2048) * 256 + h * 32;
    const bf16* vbase = vT + (size_t)(bh * 32) * 2048;
    int kr = tid >> 2, kc = (tid & 3) * 8;
    int dr = tid >> 3, nc2 = (tid & 7) * 8;
    float lsum = 0.f;
    // ---- pass A: row sums ----
    {
        *(b16x8*)&sK[kr][kc] = *(const b16x8*)(kbase + (size_t)kr * 256 + kc);
        __syncthreads();
        for (int kt = 0; kt < 2048; kt += 64) {
            bool more = (kt + 64) < 2048;
            b16x8 kst;
            if (more)
                kst = *(const b16x8*)(kbase + (size_t)(kt + 64 + kr) * 256 + kc);  // issue early
            b16x8 kf[4];
#pragma unroll
            for (int n = 0; n < 4; n++) kf[n] = *(b16x8*)&sK[n * 16 + ll][8 * lg];
            f32x4 s[4];
#pragma unroll
            for (int n = 0; n < 4; n++) {
                f32x4 z = {};
                s[n] = MFMA16(kf[n], qf, z);
            }
#pragma unroll
            for (int n = 0; n < 4; n++) {
                f32x4 mk = *(const f32x4*)&mrow[kt + n * 16 + lg * 4];
#pragma unroll
                for (int r = 0; r < 4; r++) lsum += exp2f(s[n][r] + mk[r]);
            }
            __syncthreads();  // all fragment reads done
            if (more) *(b16x8*)&sK[kr][kc] = kst;
            __syncthreads();  // staging visible
        }
    }
    lsum += __shfl_xor(lsum, 16, 64);
    lsum += __shfl_xor(lsum, 32, 64);
    float linv = 1.f / lsum;
    // ---- pass B: recompute, write normalized attn (NT), accumulate O = P@V ----
    f32x4 o[2] = {};
    float* outb = attn + (size_t)(bh * 2048 + qrow0) * 2048;
    *(b16x8*)&sK[kr][kc] = *(const b16x8*)(kbase + (size_t)kr * 256 + kc);
    *(b16x8*)&sV[dr][nc2] = *(const b16x8*)(vbase + (size_t)dr * 2048 + nc2);
    __syncthreads();
    for (int kt = 0; kt < 2048; kt += 64) {
        bool more = (kt + 64) < 2048;
        b16x8 kst, vst;
        if (more) {
            kst = *(const b16x8*)(kbase + (size_t)(kt + 64 + kr) * 256 + kc);   // issue early
            vst = *(const b16x8*)(vbase + (size_t)dr * 2048 + kt + 64 + nc2);  // issue early
        }
        b16x8 kf[4], vf[2][2];
#pragma unroll
        for (int n = 0; n < 4; n++) kf[n] = *(b16x8*)&sK[n * 16 + ll][8 * lg];
#pragma unroll
        for (int ks = 0; ks < 2; ks++)
#pragma unroll
            for (int j = 0; j < 2; j++)
                vf[ks][j] = *(b16x8*)&sV[j * 16 + ll][ks * 32 + 8 * lg];
        f32x4 s[4];
#pragma unroll
        for (int n = 0; n < 4; n++) {
            f32x4 z = {};
            s[n] = MFMA16(kf[n], qf, z);
        }
#pragma unroll
        for (int n = 0; n < 4; n++) {
            f32x4 mk = *(const f32x4*)&mrow[kt + n * 16 + lg * 4];
            f32x4 ov;
#pragma unroll
            for (int r = 0; r < 4; r++) ov[r] = exp2f(s[n][r] + mk[r]) * linv;
            *(f32x4*)&sPf[w][ll][n * 16 + lg * 4] = ov;  // ds_write_b128 (wave-local)
        }
        // contiguous 256B f32x4 NON-TEMPORAL stores (bypass L2 allocate)
#pragma unroll
        for (int j = 0; j < 4; j++) {
            int row16 = lg + 4 * j;
            f32x4 v = *(f32x4*)&sPf[w][row16][ll * 4];
            __builtin_nontemporal_store(v, (f32x4*)(outb + (size_t)row16 * 2048 + kt + ll * 4));
        }
        // PV accumulate: fragment from f32 sPf, cvt to bf16 in-register
#pragma unroll
        for (int ks = 0; ks < 2; ks++) {
            f32x4 p0 = *(f32x4*)&sPf[w][ll][ks * 32 + 8 * lg];
            f32x4 p1 = *(f32x4*)&sPf[w][ll][ks * 32 + 8 * lg + 4];
            b16x8 pf;
#pragma unroll
            for (int i = 0; i < 4; i++) {
                pf[i] = (bf16)p0[i];
                pf[4 + i] = (bf16)p1[i];
            }
#pragma unroll
            for (int j = 0; j < 2; j++) o[j] = MFMA16(pf, vf[ks][j], o[j]);
        }
        __syncthreads();  // all sK/sV fragment reads done
        if (more) {
            *(b16x8*)&sK[kr][kc] = kst;
            *(b16x8*)&sV[dr][nc2] = vst;
        }
        __syncthreads();  // staging visible
    }
#pragma unroll
    for (int r = 0; r < 4; r++) {
        int row = b * 2048 + qrow0 + lg * 4 + r;
#pragma unroll
        for (int j = 0; j < 2; j++) {
            int col = h * 32 + j * 16 + ll;
            xO[(size_t)(row >> 5) * 16384 + (row & 31) * 256 + col] = (bf16)o[j][r];
        }
    }
}

// ====== launch 3: FC full-row + bias + idt + LayerNorm (xO hole-layout) =============
__global__ void __launch_bounds__(256) k_fcln(const bf16* __restrict__ xO,
                                              const bf16* __restrict__ Wfcb,
                                              const float* __restrict__ bias,
                                              const float* __restrict__ idt,
                                              const float* __restrict__ lnw,
                                              const float* __restrict__ lnb,
                                              float* __restrict__ out) {
    __shared__ __align__(16) bf16 sA[32][264];
    __shared__ __align__(16) bf16 sB[256][40];
    __shared__ float sRed[4][32][2];
    int tid = threadIdx.x;
    int w = tid >> 6, l = tid & 63, lg = l >> 4, ll = l & 15;
    int t = blockIdx.x;  // rows 32t..32t+31
#pragma unroll
    for (int c = 0; c < 4; c++) {
        int col = (tid & 7) * 8 + c * 64;
        *(b16x8*)&sA[tid >> 3][col] =
            *(const b16x8*)(xO + (size_t)t * 16384 + (tid >> 3) * 256 + col);
    }
    __syncthreads();
    f32x4 acc[2][4] = {};
#pragma unroll
    for (int k0 = 0; k0 < 256; k0 += 32) {
        if (k0) __syncthreads();
#pragma unroll
        for (int c = 0; c < 4; c++)
            *(b16x8*)&sB[tid][c * 8] = *(const b16x8*)(Wfcb + (size_t)tid * 256 + k0 + c * 8);
        __syncthreads();
        b16x8 af[2];
#pragma unroll
        for (int i = 0; i < 2; i++) af[i] = *(b16x8*)&sA[i * 16 + ll][k0 + 8 * lg];
#pragma unroll
        for (int j = 0; j < 4; j++) {
            b16x8 bfr = *(b16x8*)&sB[w * 64 + j * 16 + ll][8 * lg];
#pragma unroll
            for (int i = 0; i < 2; i++) acc[i][j] = MFMA16(af[i], bfr, acc[i][j]);
        }
    }
    float bcol[4], wcol[4], bbl[4];
#pragma unroll
    for (int j = 0; j < 4; j++) {
        int col = w * 64 + j * 16 + ll;
        bcol[j] = bias[col];
        wcol[j] = lnw[col];
        bbl[j] = lnb[col];
    }
#pragma unroll
    for (int i = 0; i < 2; i++)
#pragma unroll
        for (int r = 0; r < 4; r++) {
            int row32 = i * 16 + lg * 4 + r;
            int grow = t * 32 + row32;
            float a = 0.f, b2 = 0.f;
#pragma unroll
            for (int j = 0; j < 4; j++) {
                float xv = acc[i][j][r] + bcol[j] + idt[(size_t)grow * 256 + w * 64 + j * 16 + ll];
                acc[i][j][r] = xv;
                a += xv;
                b2 += xv * xv;
            }
#pragma unroll
            for (int off = 1; off < 16; off <<= 1) {
                a += __shfl_xor(a, off, 64);
                b2 += __shfl_xor(b2, off, 64);
            }
            if (ll == 0) {
                sRed[w][row32][0] = a;
                sRed[w][row32][1] = b2;
            }
        }
    __syncthreads();
#pragma unroll
    for (int i = 0; i < 2; i++)
#pragma unroll
        for (int r = 0; r < 4; r++) {
            int row32 = i * 16 + lg * 4 + r;
            int grow = t * 32 + row32;
            float st = sRed[0][row32][0] + sRed[1][row32][0] + sRed[2][row32][0] + sRed[3][row32][0];
            float st2 = sRed[0][row32][1] + sRed[1][row32][1] + sRed[2][row32][1] + sRed[3][row32][1];
            float mu = st * (1.f / 256.f);
            float var = st2 * (1.f / 256.f) - mu * mu;
            float rstd = rsqrtf(var + 1e-5f);
#pragma unroll
            for (int j = 0; j < 4; j++)
                out[(size_t)grow * 256 + w * 64 + j * 16 + ll] =
                    (acc[i][j][r] - mu) * rstd * wcol[j] + bbl[j];
        }
}

extern "C" void kernel_launch(void* const* d_in, const int* in_sizes, int n_in,
                              void* d_out, int out_size, void* d_ws, size_t ws_size,
                              hipStream_t stream) {
    const float* k_in = (const float*)d_in[0];
    const float* v_in = (const float*)d_in[1];
    const float* q_in = (const float*)d_in[2];
    const float* idt  = (const float*)d_in[3];
    const int* svalid = (const int*)d_in[4];
    const float* Wqk  = (const float*)d_in[5];
    const float* Wfc  = (const float*)d_in[6];
    const float* bfc  = (const float*)d_in[7];
    const float* lnw  = (const float*)d_in[8];
    const float* lnb  = (const float*)d_in[9];

    float* out_ln = (float*)d_out;               // 8192*256 f32
    float* attn = out_ln + 2097152;              // (B*H, Nq, Ns) f32

    // workspace layout (~12.2 MB)
    char* ws = (char*)d_ws;
    bf16* ph     = (bf16*)ws;                    // 16384*256 bf16 (q rows pre-scaled)
    bf16* vT     = (bf16*)(ws + 8388608);        // 32*32*2048 bf16 = 4 MB
    bf16* Wfcb   = (bf16*)(ws + 12582912);       // 65536 bf16
    float* maskf = (float*)(ws + 12713984);      // 8192 f32

    // xO parks in out_ln region, tile t at byte 32768*t (fcln block t is sole reader
    // and sole overwriter after LDS staging) -> race-free.
    bf16* xO = (bf16*)out_ln;

    k_prep<<<2081, 256, 0, stream>>>(q_in, k_in, Wqk, v_in, Wfc, svalid, ph, vT, Wfcb, maskf);
    k_attn<<<1024, 256, 0, stream>>>(ph, vT, maskf, xO, attn);
    k_fcln<<<256, 256, 0, stream>>>(xO, Wfcb, bfc, idt, lnw, lnb, out_ln);
}